// Round 9
// baseline (211.902 us; speedup 1.0000x reference)
//
#include <hip/hip_runtime.h>
#include <hip/hip_fp16.h>

#define A     96
#define DET0  256
#define NZ    32
#define NY    256
#define NX    256
#define T     256
#define LAMB  0.01f

// ws layout (floats):
//   trig  : [A][2]            @ 0        (192, padded to 256)
//   res_t : [A][DET0][NZ]     @ 256      (786,432) fp32, seeded -p_perm by k_transpose
//   vol_h : [NY][NX][NZ] f16  @ 786,688  (2,097,152 ushorts = 1,048,576 floats)
//   part  : [C][A][DET0][NZ]  @ 1,835,264
#define TRIG_OFF  0
#define REST_OFF  256
#define VOLB_OFF  786688
#define PART_OFF  1835264
#define RES_ELEMS 786432

// acc += f16half(v) * w, forced v_fma_mix_f32.
__device__ __forceinline__ void accp_mix(float& a0, float& a1, unsigned v, float w) {
    asm("v_fma_mix_f32 %0, %2, %3, %0 op_sel:[0,0,0] op_sel_hi:[1,0,0]\n\t"
        "v_fma_mix_f32 %1, %2, %3, %1 op_sel:[1,0,0] op_sel_hi:[1,0,0]"
        : "+v"(a0), "+v"(a1)
        : "v"(v), "v"(w));
}
__device__ __forceinline__ void acc8h(float* acc, uint4 q, float w) {
    accp_mix(acc[0], acc[1], q.x, w);
    accp_mix(acc[2], acc[3], q.y, w);
    accp_mix(acc[4], acc[5], q.z, w);
    accp_mix(acc[6], acc[7], q.w, w);
}

// ---------------------------------------------------------------------------
// K1: transpose vol (z,y,x) fp32 -> vol_h (y,x,z) f16; fill trig table;
//     seed res_t = -p_perm. grid (NX/64, NY), block 256
__global__ __launch_bounds__(256) void k_transpose(const float* __restrict__ src,
                                                   unsigned short* __restrict__ vol_h,
                                                   float* __restrict__ trig,
                                                   const float* __restrict__ p,
                                                   float* __restrict__ res_t) {
    __shared__ float lds[64 * 33];
    const int y   = blockIdx.y;
    const int x0  = blockIdx.x * 64;
    const int tid = threadIdx.x;

    if (blockIdx.x == 0 && y == 0 && tid < A) {
        float th = (float)tid * (float)(3.14159265358979323846 / (double)A);
        trig[2 * tid]     = cosf(th);
        trig[2 * tid + 1] = sinf(th);
    }

    const int xr = tid & 63;
    const int zr = tid >> 6;
    #pragma unroll
    for (int pz = 0; pz < 8; ++pz) {
        int z = pz * 4 + zr;
        lds[xr * 33 + z] = src[(z * NY + y) * NX + x0 + xr];
    }
    __syncthreads();
    const int zw = tid & 31;
    const int xw = tid >> 5;
    #pragma unroll
    for (int px = 0; px < 8; ++px) {
        int xi = px * 8 + xw;
        vol_h[(y * NX + x0 + xi) * NZ + zw] =
            __half_as_ushort(__float2half(lds[xi * 33 + zw]));
    }

    if (y < A) {
        const int a  = y;
        const int u0 = blockIdx.x * 64;
        __syncthreads();
        const int col = tid & 63;
        const int r0  = tid >> 6;
        #pragma unroll
        for (int i = 0; i < 8; ++i) {
            int r = i * 4 + r0;
            lds[r * 65 + col] = p[a * 8192 + r * 256 + u0 + col];
        }
        __syncthreads();
        const int ul = tid >> 2;
        const int zb = (tid & 3) * 8;
        float o[8];
        #pragma unroll
        for (int k = 0; k < 8; ++k) {
            int z = zb + k;
            int r = ((z & 7) << 2) + (z >> 3);
            o[k] = -lds[r * 65 + ul];
        }
        float4* d = (float4*)(res_t + (a * DET0 + u0 + ul) * NZ + zb);
        d[0] = make_float4(o[0], o[1], o[2], o[3]);
        d[1] = make_float4(o[4], o[5], o[6], o[7]);
    }
}

// ---------------------------------------------------------------------------
__device__ __forceinline__ void rng(float g, float b, float L, float H,
                                    float& lo, float& hi) {
    if (fabsf(g) > 1e-5f) {
        float r0 = (L - b) / g, r1 = (H - b) / g;
        lo = fminf(r0, r1); hi = fmaxf(r0, r1);
    } else {
        bool in = (b >= L && b <= H);
        lo = in ? -1e9f : 1e9f;
        hi = in ? 1e9f : -1e9f;
    }
}
__device__ __forceinline__ int clampi(float v) {
    return (int)fminf(fmaxf(v, -2.f), 258.f);
}

__device__ __forceinline__ void sample_edge(const char* base, float ix, float iy,
                                            float* acc) {
    float xf = floorf(ix), yf = floorf(iy);
    float fx = ix - xf, fy = iy - yf;
    int x0 = (int)xf, y0 = (int)yf;
    float wx0 = 1.f - fx, wx1 = fx, wy0 = 1.f - fy, wy1 = fy;
    if ((unsigned)x0 >= NX)       wx0 = 0.f;
    if ((unsigned)(x0 + 1) >= NX) wx1 = 0.f;
    if ((unsigned)y0 >= NY)       wy0 = 0.f;
    if ((unsigned)(y0 + 1) >= NY) wy1 = 0.f;
    if ((wx0 == 0.f && wx1 == 0.f) || (wy0 == 0.f && wy1 == 0.f)) return;
    int cx0 = min(max(x0, 0), NX - 1);
    int cx1 = min(max(x0 + 1, 0), NX - 1);
    int cy0 = min(max(y0, 0), NY - 1);
    int cy1 = min(max(y0 + 1, 0), NY - 1);
    uint4 q00 = *(const uint4*)(base + ((size_t)((cy0 << 8) + cx0) << 6));
    uint4 q01 = *(const uint4*)(base + ((size_t)((cy0 << 8) + cx1) << 6));
    uint4 q10 = *(const uint4*)(base + ((size_t)((cy1 << 8) + cx0) << 6));
    uint4 q11 = *(const uint4*)(base + ((size_t)((cy1 << 8) + cx1) << 6));
    acc8h(acc, q00, wy0 * wx0);
    acc8h(acc, q01, wy0 * wx1);
    acc8h(acc, q10, wy1 * wx0);
    acc8h(acc, q11, wy1 * wx1);
}

// ---------------------------------------------------------------------------
// K2: forward projection (round-7 config: per-ray slicing, v_fma_mix, no pipeline).
// grid (4 u-groups, C ray-slices, A), block 256
__global__ __launch_bounds__(256) void k_forward(const unsigned short* __restrict__ vol_h,
                                                 const float* __restrict__ trig,
                                                 float* __restrict__ part) {
    const int tid = threadIdx.x;
    const int a   = blockIdx.z;
    const int u   = blockIdx.x * 64 + (tid >> 2);
    const int zq  = tid & 3;
    const int cid = blockIdx.y;
    const int C   = gridDim.y;

    const float c = trig[2 * a];
    const float s = trig[2 * a + 1];
    const float uu = (float)u - 127.5f;
    const float bx = fmaf(-uu, s, 127.5f);
    const float by = fmaf(uu, c, 127.5f);

    float lo1, hi1, lo2, hi2;
    rng(c, bx, -1.f, 256.f, lo1, hi1);
    rng(s, by, -1.f, 256.f, lo2, hi2);
    float fl = fmaxf(lo1, lo2), fh = fminf(hi1, hi2);
    int F0 = max(0,     clampi(ceilf(fl + 127.5f)));
    int F1 = min(T - 1, clampi(floorf(fh + 127.5f)));
    int len = F1 - F0 + 1; if (len < 0) len = 0;
    int b0 = F0 + (len * cid) / C;
    int b1 = F0 + (len * (cid + 1)) / C - 1;
    rng(c, bx, 1.f, 253.5f, lo1, hi1);
    rng(s, by, 1.f, 253.5f, lo2, hi2);
    float il = fmaxf(lo1, lo2), ih = fminf(hi1, hi2);
    int tI0 = max(clampi(ceilf(il + 127.5f)) + 1, b0);
    int tI1 = min(clampi(floorf(ih + 127.5f)) - 1, b1);
    if (tI0 > tI1) { tI0 = b1 + 1; tI1 = b1; }

    const char* base = (const char*)vol_h + zq * 16;
    float acc[8];
    #pragma unroll
    for (int k = 0; k < 8; ++k) acc[k] = 0.f;

    for (int t = b0; t < tI0; ++t) {
        float ttf = (float)t - 127.5f;
        sample_edge(base, fmaf(ttf, c, bx), fmaf(ttf, s, by), acc);
    }
    for (int t = tI0; t <= tI1; ++t) {
        float ttf = (float)t - 127.5f;
        float ix = fmaf(ttf, c, bx);
        float iy = fmaf(ttf, s, by);
        float xf = floorf(ix), yf = floorf(iy);
        float fx = ix - xf, fy = iy - yf;
        int row = ((int)yf << 8) + (int)xf;
        const char* p0 = base + ((size_t)row << 6);
        uint4 q00 = *(const uint4*)(p0);
        uint4 q01 = *(const uint4*)(p0 + 64);
        uint4 q10 = *(const uint4*)(p0 + 16384);
        uint4 q11 = *(const uint4*)(p0 + 16384 + 64);
        float wx0 = 1.f - fx, wy0 = 1.f - fy;
        acc8h(acc, q00, wy0 * wx0);
        acc8h(acc, q01, wy0 * fx);
        acc8h(acc, q10, fy * wx0);
        acc8h(acc, q11, fy * fx);
    }
    for (int t = tI1 + 1; t <= b1; ++t) {
        float ttf = (float)t - 127.5f;
        sample_edge(base, fmaf(ttf, c, bx), fmaf(ttf, s, by), acc);
    }

    float4* dst = (float4*)(part + (size_t)cid * RES_ELEMS +
                            ((a * DET0 + u) * NZ + zq * 8));
    dst[0] = make_float4(acc[0], acc[1], acc[2], acc[3]);
    dst[1] = make_float4(acc[4], acc[5], acc[6], acc[7]);
}

// ---------------------------------------------------------------------------
// K3: res_t (seeded -p_perm) += sum_c part[c]. grid (768), block 256
__global__ __launch_bounds__(256) void k_combine(const float* __restrict__ part,
                                                 float* __restrict__ res_t,
                                                 int C) {
    const int j4 = blockIdx.x * 256 + threadIdx.x;
    float4 v = ((const float4*)res_t)[j4];
    for (int c = 0; c < C; ++c) {
        float4 w = ((const float4*)(part + (size_t)c * RES_ELEMS))[j4];
        v.x += w.x; v.y += w.y; v.z += w.z; v.w += w.w;
    }
    ((float4*)res_t)[j4] = v;
}

// ---------------------------------------------------------------------------
// K4: backprojection v3 — LDS-staged u-window, y-tile=2, double-buffered.
// Per (block, angle) all taps fall in a contiguous u-window of <=34 rows
// (span = 31|s|+|c|+2). Stage it with coalesced float4 loads (adaptive count),
// gather from LDS (144B rows + 16B-unit XOR swizzle, G4). Loads for angle a+1
// issued before compute of angle a (T14); ONE barrier per angle.
// thread = (xs = tid>>3 of 32, zq = tid&7; 4 z per lane). grid (NX/32, NY/2).
#define BWIN 36              // staged rows cap (>= 34 worst case)
#define BROW 144             // LDS row stride bytes (128B data + 16B pad)
__global__ __launch_bounds__(256) void k_backward(const float* __restrict__ res_t,
                                                  const float* __restrict__ trig,
                                                  float* __restrict__ out) {
    __shared__ float smem[2 * BWIN * (BROW / 4)];  // 10,368 B; tail reused as ob staging
    const int tid = threadIdx.x;
    const int xb  = blockIdx.x * 32;
    const int y0  = blockIdx.y * 2;
    const int xs  = tid >> 3;
    const int zq  = tid & 7;
    const float xt  = (float)(xb + xs) - 127.5f;
    const float yt0 = (float)y0 - 127.5f;
    const float yt1 = yt0 + 1.0f;
    const float xlo = (float)xb - 127.5f;
    const float xhi = (float)(xb + 31) - 127.5f;

    float4 acc0 = make_float4(0.f, 0.f, 0.f, 0.f);
    float4 acc1 = make_float4(0.f, 0.f, 0.f, 0.f);

    // ---- per-angle uniform window: U0 = floor(min ub over block), nch chunks
    #define WINDOW(aa, U0v, nchv) {                                        \
        float cc_ = trig[2 * (aa)], ss_ = trig[2 * (aa) + 1];              \
        float k0_ = fmaf(yt0, cc_, 127.5f);                                \
        float k1_ = fmaf(yt1, cc_, 127.5f);                                \
        float u00 = fmaf(-xlo, ss_, k0_), u01 = fmaf(-xhi, ss_, k0_);      \
        float u10 = fmaf(-xlo, ss_, k1_), u11 = fmaf(-xhi, ss_, k1_);      \
        float mn = fminf(fminf(u00, u01), fminf(u10, u11));                \
        float mx = fmaxf(fmaxf(u00, u01), fmaxf(u10, u11));                \
        U0v = (int)floorf(mn);                                             \
        int rows_ = (int)floorf(mx) + 2 - U0v;  /* taps [U0, floor(mx)+1] */ \
        nchv = rows_ * 8;                       /* 16B chunks to stage */  \
    }
    #define STAGE_LOAD(aa, U0v, nchv, r0, r1) {                            \
        if (tid < (nchv)) {                                                \
            int rr = tid >> 3, sl = tid & 7;                               \
            int row = min(max((U0v) + rr, 0), DET0 - 1);                   \
            r0 = *(const float4*)(res_t + (((aa) * DET0 + row) << 5) + sl * 4); \
        }                                                                  \
        if (tid + 256 < (nchv)) {                                          \
            int cch = tid + 256;                                           \
            int rr = cch >> 3, sl = cch & 7;                               \
            int row = min(max((U0v) + rr, 0), DET0 - 1);                   \
            r1 = *(const float4*)(res_t + (((aa) * DET0 + row) << 5) + sl * 4); \
        }                                                                  \
    }
    #define STAGE_WRITE(bufv, nchv, r0, r1) {                              \
        char* bb = (char*)(smem + (bufv) * (BWIN * BROW / 4));             \
        if (tid < (nchv)) {                                                \
            int rr = tid >> 3, sl = tid & 7;                               \
            *(float4*)(bb + rr * BROW + ((sl ^ (rr & 7)) << 4)) = r0;      \
        }                                                                  \
        if (tid + 256 < (nchv)) {                                          \
            int cch = tid + 256;                                           \
            int rr = cch >> 3, sl = cch & 7;                               \
            *(float4*)(bb + rr * BROW + ((sl ^ (rr & 7)) << 4)) = r1;      \
        }                                                                  \
    }

    int U0c, nchc, U0n, nchn;
    float4 s0, s1;
    WINDOW(0, U0c, nchc);
    STAGE_LOAD(0, U0c, nchc, s0, s1);
    STAGE_WRITE(0, nchc, s0, s1);
    __syncthreads();

    for (int a = 0; a < A; ++a) {
        const int cur = a & 1;
        if (a + 1 < A) {
            WINDOW(a + 1, U0n, nchn);
            STAGE_LOAD(a + 1, U0n, nchn, s0, s1);   // issue early; lands under compute
        }
        const float cc = trig[2 * a];
        const float ss = trig[2 * a + 1];
        const char* bb = (const char*)(smem + cur * (BWIN * BROW / 4));
        // ---- y = y0
        {
            float ub = fmaf(-xt, ss, fmaf(yt0, cc, 127.5f));
            float uf = floorf(ub);
            float fu = ub - uf;
            int i0 = (int)uf;
            float w0 = ((unsigned)i0 < DET0) ? (1.f - fu) : 0.f;
            float w1 = ((unsigned)(i0 + 1) < DET0) ? fu : 0.f;
            int idx = i0 - U0c;          // in [0, rows-2] by construction
            int id1 = idx + 1;
            float4 v0 = *(const float4*)(bb + idx * BROW + ((zq ^ (idx & 7)) << 4));
            float4 v1 = *(const float4*)(bb + id1 * BROW + ((zq ^ (id1 & 7)) << 4));
            acc0.x = fmaf(w0, v0.x, fmaf(w1, v1.x, acc0.x));
            acc0.y = fmaf(w0, v0.y, fmaf(w1, v1.y, acc0.y));
            acc0.z = fmaf(w0, v0.z, fmaf(w1, v1.z, acc0.z));
            acc0.w = fmaf(w0, v0.w, fmaf(w1, v1.w, acc0.w));
        }
        // ---- y = y0 + 1
        {
            float ub = fmaf(-xt, ss, fmaf(yt1, cc, 127.5f));
            float uf = floorf(ub);
            float fu = ub - uf;
            int i0 = (int)uf;
            float w0 = ((unsigned)i0 < DET0) ? (1.f - fu) : 0.f;
            float w1 = ((unsigned)(i0 + 1) < DET0) ? fu : 0.f;
            int idx = i0 - U0c;
            int id1 = idx + 1;
            float4 v0 = *(const float4*)(bb + idx * BROW + ((zq ^ (idx & 7)) << 4));
            float4 v1 = *(const float4*)(bb + id1 * BROW + ((zq ^ (id1 & 7)) << 4));
            acc1.x = fmaf(w0, v0.x, fmaf(w1, v1.x, acc1.x));
            acc1.y = fmaf(w0, v0.y, fmaf(w1, v1.y, acc1.y));
            acc1.z = fmaf(w0, v0.z, fmaf(w1, v1.z, acc1.z));
            acc1.w = fmaf(w0, v0.w, fmaf(w1, v1.w, acc1.w));
        }
        if (a + 1 < A) {
            STAGE_WRITE(cur ^ 1, nchn, s0, s1);     // disjoint buffer from reads above
            U0c = U0n;
        }
        __syncthreads();                            // one barrier per angle
    }

    // ---- output transpose through LDS (reuse smem), per y
    #pragma unroll 1
    for (int yt = 0; yt < 2; ++yt) {
        float4 acc = yt ? acc1 : acc0;
        smem[(zq * 4 + 0) * 33 + xs] = acc.x;
        smem[(zq * 4 + 1) * 33 + xs] = acc.y;
        smem[(zq * 4 + 2) * 33 + xs] = acc.z;
        smem[(zq * 4 + 3) * 33 + xs] = acc.w;
        __syncthreads();
        int z  = tid >> 3;
        int x4 = (tid & 7) * 4;
        float4 o = make_float4(smem[z * 33 + x4],     smem[z * 33 + x4 + 1],
                               smem[z * 33 + x4 + 2], smem[z * 33 + x4 + 3]);
        float4* dst = (float4*)(out + (size_t)z * (NY * NX) + (y0 + yt) * NX + xb + x4);
        *dst = make_float4(-LAMB * o.x, -LAMB * o.y, -LAMB * o.z, -LAMB * o.w);
        __syncthreads();
    }
}

// ---------------------------------------------------------------------------
extern "C" void kernel_launch(void* const* d_in, const int* in_sizes, int n_in,
                              void* d_out, int out_size, void* d_ws, size_t ws_size,
                              hipStream_t stream) {
    const float* x = (const float*)d_in[0];   // (1,1,32,256,256)
    const float* p = (const float*)d_in[1];   // (1,1,384,8,256)
    float* out = (float*)d_out;               // (1,1,32,256,256)
    float* ws  = (float*)d_ws;

    float*          trig  = ws + TRIG_OFF;
    float*          res_t = ws + REST_OFF;
    unsigned short* vol_h = (unsigned short*)(ws + VOLB_OFF);
    float*          part  = ws + PART_OFF;

    size_t avail = ws_size / 4;
    int C = 8;
    while (C > 1 && (size_t)PART_OFF + (size_t)C * RES_ELEMS > avail) C >>= 1;

    k_transpose<<<dim3(NX / 64, NY), 256, 0, stream>>>(x, vol_h, trig, p, res_t);
    k_forward  <<<dim3(4, C, A), 256, 0, stream>>>(vol_h, trig, part);
    k_combine  <<<dim3(RES_ELEMS / 4 / 256), 256, 0, stream>>>(part, res_t, C);
    k_backward <<<dim3(NX / 32, NY / 2), 256, 0, stream>>>(res_t, trig, out);
}

// Round 10
// 192.425 us; speedup vs baseline: 1.1012x; 1.1012x over previous
//
#include <hip/hip_runtime.h>
#include <hip/hip_fp16.h>

#define A     96
#define DET0  256
#define NZ    32
#define NY    256
#define NX    256
#define T     256
#define LAMB  0.01f

// ws layout (floats):
//   trig  : [A][2]            @ 0        (192, padded to 256; padding absorbs the
//                                         harmless -128B zero-weight tap in k_backward)
//   res_t : [A][DET0][NZ]     @ 256      (786,432) fp32, seeded -p_perm by k_transpose
//   vol_h : [NY][NX][NZ] f16  @ 786,688  (2,097,152 ushorts = 1,048,576 floats)
//   part  : [C][A][DET0][NZ]  @ 1,835,264
#define TRIG_OFF  0
#define REST_OFF  256
#define VOLB_OFF  786688
#define PART_OFF  1835264
#define RES_ELEMS 786432

// acc += f16half(v) * w, forced v_fma_mix_f32.
__device__ __forceinline__ void accp_mix(float& a0, float& a1, unsigned v, float w) {
    asm("v_fma_mix_f32 %0, %2, %3, %0 op_sel:[0,0,0] op_sel_hi:[1,0,0]\n\t"
        "v_fma_mix_f32 %1, %2, %3, %1 op_sel:[1,0,0] op_sel_hi:[1,0,0]"
        : "+v"(a0), "+v"(a1)
        : "v"(v), "v"(w));
}
__device__ __forceinline__ void acc8h(float* acc, uint4 q, float w) {
    accp_mix(acc[0], acc[1], q.x, w);
    accp_mix(acc[2], acc[3], q.y, w);
    accp_mix(acc[4], acc[5], q.z, w);
    accp_mix(acc[6], acc[7], q.w, w);
}

// ---------------------------------------------------------------------------
// K1: transpose vol (z,y,x) fp32 -> vol_h (y,x,z) f16; fill trig table;
//     seed res_t = -p_perm. grid (NX/64, NY), block 256
__global__ __launch_bounds__(256) void k_transpose(const float* __restrict__ src,
                                                   unsigned short* __restrict__ vol_h,
                                                   float* __restrict__ trig,
                                                   const float* __restrict__ p,
                                                   float* __restrict__ res_t) {
    __shared__ float lds[64 * 33];
    const int y   = blockIdx.y;
    const int x0  = blockIdx.x * 64;
    const int tid = threadIdx.x;

    if (blockIdx.x == 0 && y == 0 && tid < A) {
        float th = (float)tid * (float)(3.14159265358979323846 / (double)A);
        trig[2 * tid]     = cosf(th);
        trig[2 * tid + 1] = sinf(th);
    }

    const int xr = tid & 63;
    const int zr = tid >> 6;
    #pragma unroll
    for (int pz = 0; pz < 8; ++pz) {
        int z = pz * 4 + zr;
        lds[xr * 33 + z] = src[(z * NY + y) * NX + x0 + xr];
    }
    __syncthreads();
    const int zw = tid & 31;
    const int xw = tid >> 5;
    #pragma unroll
    for (int px = 0; px < 8; ++px) {
        int xi = px * 8 + xw;
        vol_h[(y * NX + x0 + xi) * NZ + zw] =
            __half_as_ushort(__float2half(lds[xi * 33 + zw]));
    }

    if (y < A) {
        const int a  = y;
        const int u0 = blockIdx.x * 64;
        __syncthreads();
        const int col = tid & 63;
        const int r0  = tid >> 6;
        #pragma unroll
        for (int i = 0; i < 8; ++i) {
            int r = i * 4 + r0;
            lds[r * 65 + col] = p[a * 8192 + r * 256 + u0 + col];
        }
        __syncthreads();
        const int ul = tid >> 2;
        const int zb = (tid & 3) * 8;
        float o[8];
        #pragma unroll
        for (int k = 0; k < 8; ++k) {
            int z = zb + k;
            int r = ((z & 7) << 2) + (z >> 3);
            o[k] = -lds[r * 65 + ul];
        }
        float4* d = (float4*)(res_t + (a * DET0 + u0 + ul) * NZ + zb);
        d[0] = make_float4(o[0], o[1], o[2], o[3]);
        d[1] = make_float4(o[4], o[5], o[6], o[7]);
    }
}

// ---------------------------------------------------------------------------
__device__ __forceinline__ void rng(float g, float b, float L, float H,
                                    float& lo, float& hi) {
    if (fabsf(g) > 1e-5f) {
        float r0 = (L - b) / g, r1 = (H - b) / g;
        lo = fminf(r0, r1); hi = fmaxf(r0, r1);
    } else {
        bool in = (b >= L && b <= H);
        lo = in ? -1e9f : 1e9f;
        hi = in ? 1e9f : -1e9f;
    }
}
__device__ __forceinline__ int clampi(float v) {
    return (int)fminf(fmaxf(v, -2.f), 258.f);
}

__device__ __forceinline__ void sample_edge(const char* base, float ix, float iy,
                                            float* acc) {
    float xf = floorf(ix), yf = floorf(iy);
    float fx = ix - xf, fy = iy - yf;
    int x0 = (int)xf, y0 = (int)yf;
    float wx0 = 1.f - fx, wx1 = fx, wy0 = 1.f - fy, wy1 = fy;
    if ((unsigned)x0 >= NX)       wx0 = 0.f;
    if ((unsigned)(x0 + 1) >= NX) wx1 = 0.f;
    if ((unsigned)y0 >= NY)       wy0 = 0.f;
    if ((unsigned)(y0 + 1) >= NY) wy1 = 0.f;
    if ((wx0 == 0.f && wx1 == 0.f) || (wy0 == 0.f && wy1 == 0.f)) return;
    int cx0 = min(max(x0, 0), NX - 1);
    int cx1 = min(max(x0 + 1, 0), NX - 1);
    int cy0 = min(max(y0, 0), NY - 1);
    int cy1 = min(max(y0 + 1, 0), NY - 1);
    uint4 q00 = *(const uint4*)(base + ((size_t)((cy0 << 8) + cx0) << 6));
    uint4 q01 = *(const uint4*)(base + ((size_t)((cy0 << 8) + cx1) << 6));
    uint4 q10 = *(const uint4*)(base + ((size_t)((cy1 << 8) + cx0) << 6));
    uint4 q11 = *(const uint4*)(base + ((size_t)((cy1 << 8) + cx1) << 6));
    acc8h(acc, q00, wy0 * wx0);
    acc8h(acc, q01, wy0 * wx1);
    acc8h(acc, q10, wy1 * wx0);
    acc8h(acc, q11, wy1 * wx1);
}

// ---------------------------------------------------------------------------
// K2: forward projection (round-7 config: per-ray slicing, v_fma_mix, no pipeline).
// grid (4 u-groups, C ray-slices, A), block 256
__global__ __launch_bounds__(256) void k_forward(const unsigned short* __restrict__ vol_h,
                                                 const float* __restrict__ trig,
                                                 float* __restrict__ part) {
    const int tid = threadIdx.x;
    const int a   = blockIdx.z;
    const int u   = blockIdx.x * 64 + (tid >> 2);
    const int zq  = tid & 3;
    const int cid = blockIdx.y;
    const int C   = gridDim.y;

    const float c = trig[2 * a];
    const float s = trig[2 * a + 1];
    const float uu = (float)u - 127.5f;
    const float bx = fmaf(-uu, s, 127.5f);
    const float by = fmaf(uu, c, 127.5f);

    float lo1, hi1, lo2, hi2;
    rng(c, bx, -1.f, 256.f, lo1, hi1);
    rng(s, by, -1.f, 256.f, lo2, hi2);
    float fl = fmaxf(lo1, lo2), fh = fminf(hi1, hi2);
    int F0 = max(0,     clampi(ceilf(fl + 127.5f)));
    int F1 = min(T - 1, clampi(floorf(fh + 127.5f)));
    int len = F1 - F0 + 1; if (len < 0) len = 0;
    int b0 = F0 + (len * cid) / C;
    int b1 = F0 + (len * (cid + 1)) / C - 1;
    rng(c, bx, 1.f, 253.5f, lo1, hi1);
    rng(s, by, 1.f, 253.5f, lo2, hi2);
    float il = fmaxf(lo1, lo2), ih = fminf(hi1, hi2);
    int tI0 = max(clampi(ceilf(il + 127.5f)) + 1, b0);
    int tI1 = min(clampi(floorf(ih + 127.5f)) - 1, b1);
    if (tI0 > tI1) { tI0 = b1 + 1; tI1 = b1; }

    const char* base = (const char*)vol_h + zq * 16;
    float acc[8];
    #pragma unroll
    for (int k = 0; k < 8; ++k) acc[k] = 0.f;

    for (int t = b0; t < tI0; ++t) {
        float ttf = (float)t - 127.5f;
        sample_edge(base, fmaf(ttf, c, bx), fmaf(ttf, s, by), acc);
    }
    for (int t = tI0; t <= tI1; ++t) {
        float ttf = (float)t - 127.5f;
        float ix = fmaf(ttf, c, bx);
        float iy = fmaf(ttf, s, by);
        float xf = floorf(ix), yf = floorf(iy);
        float fx = ix - xf, fy = iy - yf;
        int row = ((int)yf << 8) + (int)xf;
        const char* p0 = base + ((size_t)row << 6);
        uint4 q00 = *(const uint4*)(p0);
        uint4 q01 = *(const uint4*)(p0 + 64);
        uint4 q10 = *(const uint4*)(p0 + 16384);
        uint4 q11 = *(const uint4*)(p0 + 16384 + 64);
        float wx0 = 1.f - fx, wy0 = 1.f - fy;
        acc8h(acc, q00, wy0 * wx0);
        acc8h(acc, q01, wy0 * fx);
        acc8h(acc, q10, fy * wx0);
        acc8h(acc, q11, fy * fx);
    }
    for (int t = tI1 + 1; t <= b1; ++t) {
        float ttf = (float)t - 127.5f;
        sample_edge(base, fmaf(ttf, c, bx), fmaf(ttf, s, by), acc);
    }

    float4* dst = (float4*)(part + (size_t)cid * RES_ELEMS +
                            ((a * DET0 + u) * NZ + zq * 8));
    dst[0] = make_float4(acc[0], acc[1], acc[2], acc[3]);
    dst[1] = make_float4(acc[4], acc[5], acc[6], acc[7]);
}

// ---------------------------------------------------------------------------
// K3: res_t (seeded -p_perm) += sum_c part[c]. grid (768), block 256
__global__ __launch_bounds__(256) void k_combine(const float* __restrict__ part,
                                                 float* __restrict__ res_t,
                                                 int C) {
    const int j4 = blockIdx.x * 256 + threadIdx.x;
    float4 v = ((const float4*)res_t)[j4];
    for (int c = 0; c < C; ++c) {
        float4 w = ((const float4*)(part + (size_t)c * RES_ELEMS))[j4];
        v.x += w.x; v.y += w.y; v.z += w.z; v.w += w.w;
    }
    ((float4*)res_t)[j4] = v;
}

// ---------------------------------------------------------------------------
// K4: backprojection v4 — v5 structure with weight TABLES DELETED: ub/w0/w1/off
// recomputed inline per thread per angle (~10 VALU; VALU is idle here).
// Identical arithmetic to v5 -> bitwise-same output. LDS 41KB -> 4.2KB, so
// occupancy 3 -> 8 blocks/CU (grid 2048 = all-resident, no loop barriers) —
// the L2 tap gathers get ~2.7x more latency cover.
// thread = (xs = tid>>3 of 32, zq = tid&7; 4 z per lane). grid (NX/32, NY).
// Zero-weight clamped taps may read the trig padding harmlessly (-128B stays in ws).
__global__ __launch_bounds__(256, 8) void k_backward(const float* __restrict__ res_t,
                                                     const float* __restrict__ trig,
                                                     float* __restrict__ out) {
    __shared__ float ob[32 * 33];   // 4,224 B output staging
    const int tid = threadIdx.x;
    const int y  = blockIdx.y;
    const int xb = blockIdx.x * 32;
    const int xs = tid >> 3;
    const int zq = tid & 7;          // 4 z per lane
    const char* rbase = (const char*)res_t + zq * 16;
    const float xx = (float)(xb + xs) - 127.5f;
    const float yy = (float)y - 127.5f;

    float4 acc = make_float4(0.f, 0.f, 0.f, 0.f);
    #pragma unroll 4
    for (int a = 0; a < A; ++a) {
        float cc = trig[2 * a];      // uniform -> scalar loads
        float ss = trig[2 * a + 1];
        float ub = fmaf(-xx, ss, fmaf(yy, cc, 127.5f));
        float uf = floorf(ub);
        float fu = ub - uf;
        int i0 = (int)uf;
        float w0 = ((unsigned)i0 < DET0) ? (1.f - fu) : 0.f;
        float w1 = ((unsigned)(i0 + 1) < DET0) ? fu : 0.f;
        int c1 = min(max(i0 + 1, 0), DET0);       // 0..256; tap0 row = c1-1
        int off = ((a * DET0 + c1) * NZ - NZ) << 2;
        float4 v0 = *(const float4*)(rbase + off);
        float4 v1 = *(const float4*)(rbase + off + 128);
        acc.x = fmaf(w0, v0.x, fmaf(w1, v1.x, acc.x));
        acc.y = fmaf(w0, v0.y, fmaf(w1, v1.y, acc.y));
        acc.z = fmaf(w0, v0.z, fmaf(w1, v1.z, acc.z));
        acc.w = fmaf(w0, v0.w, fmaf(w1, v1.w, acc.w));
    }

    ob[(zq * 4 + 0) * 33 + xs] = acc.x;
    ob[(zq * 4 + 1) * 33 + xs] = acc.y;
    ob[(zq * 4 + 2) * 33 + xs] = acc.z;
    ob[(zq * 4 + 3) * 33 + xs] = acc.w;
    __syncthreads();

    const int z  = tid >> 3;
    const int x4 = (tid & 7) * 4;
    float4 o = make_float4(ob[z * 33 + x4],     ob[z * 33 + x4 + 1],
                           ob[z * 33 + x4 + 2], ob[z * 33 + x4 + 3]);
    float4* dst = (float4*)(out + (size_t)z * (NY * NX) + y * NX + xb + x4);
    *dst = make_float4(-LAMB * o.x, -LAMB * o.y, -LAMB * o.z, -LAMB * o.w);
}

// ---------------------------------------------------------------------------
extern "C" void kernel_launch(void* const* d_in, const int* in_sizes, int n_in,
                              void* d_out, int out_size, void* d_ws, size_t ws_size,
                              hipStream_t stream) {
    const float* x = (const float*)d_in[0];   // (1,1,32,256,256)
    const float* p = (const float*)d_in[1];   // (1,1,384,8,256)
    float* out = (float*)d_out;               // (1,1,32,256,256)
    float* ws  = (float*)d_ws;

    float*          trig  = ws + TRIG_OFF;
    float*          res_t = ws + REST_OFF;
    unsigned short* vol_h = (unsigned short*)(ws + VOLB_OFF);
    float*          part  = ws + PART_OFF;

    size_t avail = ws_size / 4;
    int C = 8;
    while (C > 1 && (size_t)PART_OFF + (size_t)C * RES_ELEMS > avail) C >>= 1;

    k_transpose<<<dim3(NX / 64, NY), 256, 0, stream>>>(x, vol_h, trig, p, res_t);
    k_forward  <<<dim3(4, C, A), 256, 0, stream>>>(vol_h, trig, part);
    k_combine  <<<dim3(RES_ELEMS / 4 / 256), 256, 0, stream>>>(part, res_t, C);
    k_backward <<<dim3(NX / 32, NY), 256, 0, stream>>>(res_t, trig, out);
}

// Round 11
// 191.970 us; speedup vs baseline: 1.1038x; 1.0024x over previous
//
#include <hip/hip_runtime.h>
#include <hip/hip_fp16.h>

#define A     96
#define DET0  256
#define NZ    32
#define NY    256
#define NX    256
#define T     256
#define LAMB  0.01f

// ws layout (floats):
//   trig  : [A][2]            @ 0        (192, padded to 256; padding absorbs the
//                                         harmless -64B zero-weight tap in k_backward)
//   res_t : [A][DET0][NZ] f16 @ 256      (786,432 halves = 196,608 floats), seeded
//                                         -p_perm by k_transpose, finalized by k_combine
//   vol_h : [NY][NX][NZ] f16  @ 786,688  (2,097,152 ushorts)
//   part  : [C][A][DET0][NZ]  @ 1,835,264 (fp32)
#define TRIG_OFF  0
#define REST_OFF  256
#define VOLB_OFF  786688
#define PART_OFF  1835264
#define RES_ELEMS 786432

// acc += f16half(v) * w, forced v_fma_mix_f32.
__device__ __forceinline__ void accp_mix(float& a0, float& a1, unsigned v, float w) {
    asm("v_fma_mix_f32 %0, %2, %3, %0 op_sel:[0,0,0] op_sel_hi:[1,0,0]\n\t"
        "v_fma_mix_f32 %1, %2, %3, %1 op_sel:[1,0,0] op_sel_hi:[1,0,0]"
        : "+v"(a0), "+v"(a1)
        : "v"(v), "v"(w));
}
__device__ __forceinline__ void acc8h(float* acc, uint4 q, float w) {
    accp_mix(acc[0], acc[1], q.x, w);
    accp_mix(acc[2], acc[3], q.y, w);
    accp_mix(acc[4], acc[5], q.z, w);
    accp_mix(acc[6], acc[7], q.w, w);
}
__device__ __forceinline__ unsigned pack2h(float a, float b) {
    __half2 h = __floats2half2_rn(a, b);
    return *reinterpret_cast<unsigned*>(&h);
}
__device__ __forceinline__ float2 unp2h(unsigned u) {
    __half2 h = *reinterpret_cast<__half2*>(&u);
    return __half22float2(h);
}

// ---------------------------------------------------------------------------
// K1: transpose vol (z,y,x) fp32 -> vol_h (y,x,z) f16; fill trig table;
//     seed res_t (f16) = -p_perm. grid (NX/64, NY), block 256
__global__ __launch_bounds__(256) void k_transpose(const float* __restrict__ src,
                                                   unsigned short* __restrict__ vol_h,
                                                   float* __restrict__ trig,
                                                   const float* __restrict__ p,
                                                   unsigned short* __restrict__ res_t) {
    __shared__ float lds[64 * 33];
    const int y   = blockIdx.y;
    const int x0  = blockIdx.x * 64;
    const int tid = threadIdx.x;

    if (blockIdx.x == 0 && y == 0 && tid < A) {
        float th = (float)tid * (float)(3.14159265358979323846 / (double)A);
        trig[2 * tid]     = cosf(th);
        trig[2 * tid + 1] = sinf(th);
    }

    const int xr = tid & 63;
    const int zr = tid >> 6;
    #pragma unroll
    for (int pz = 0; pz < 8; ++pz) {
        int z = pz * 4 + zr;
        lds[xr * 33 + z] = src[(z * NY + y) * NX + x0 + xr];
    }
    __syncthreads();
    const int zw = tid & 31;
    const int xw = tid >> 5;
    #pragma unroll
    for (int px = 0; px < 8; ++px) {
        int xi = px * 8 + xw;
        vol_h[(y * NX + x0 + xi) * NZ + zw] =
            __half_as_ushort(__float2half(lds[xi * 33 + zw]));
    }

    if (y < A) {
        const int a  = y;
        const int u0 = blockIdx.x * 64;
        __syncthreads();
        const int col = tid & 63;
        const int r0  = tid >> 6;
        #pragma unroll
        for (int i = 0; i < 8; ++i) {
            int r = i * 4 + r0;
            lds[r * 65 + col] = p[a * 8192 + r * 256 + u0 + col];
        }
        __syncthreads();
        const int ul = tid >> 2;
        const int zb = (tid & 3) * 8;
        float o[8];
        #pragma unroll
        for (int k = 0; k < 8; ++k) {
            int z = zb + k;
            int r = ((z & 7) << 2) + (z >> 3);
            o[k] = -lds[r * 65 + ul];
        }
        uint4 pk = make_uint4(pack2h(o[0], o[1]), pack2h(o[2], o[3]),
                              pack2h(o[4], o[5]), pack2h(o[6], o[7]));
        *(uint4*)(res_t + (a * DET0 + u0 + ul) * NZ + zb) = pk;
    }
}

// ---------------------------------------------------------------------------
__device__ __forceinline__ void rng(float g, float b, float L, float H,
                                    float& lo, float& hi) {
    if (fabsf(g) > 1e-5f) {
        float r0 = (L - b) / g, r1 = (H - b) / g;
        lo = fminf(r0, r1); hi = fmaxf(r0, r1);
    } else {
        bool in = (b >= L && b <= H);
        lo = in ? -1e9f : 1e9f;
        hi = in ? 1e9f : -1e9f;
    }
}
__device__ __forceinline__ int clampi(float v) {
    return (int)fminf(fmaxf(v, -2.f), 258.f);
}

__device__ __forceinline__ void sample_edge(const char* base, float ix, float iy,
                                            float* acc) {
    float xf = floorf(ix), yf = floorf(iy);
    float fx = ix - xf, fy = iy - yf;
    int x0 = (int)xf, y0 = (int)yf;
    float wx0 = 1.f - fx, wx1 = fx, wy0 = 1.f - fy, wy1 = fy;
    if ((unsigned)x0 >= NX)       wx0 = 0.f;
    if ((unsigned)(x0 + 1) >= NX) wx1 = 0.f;
    if ((unsigned)y0 >= NY)       wy0 = 0.f;
    if ((unsigned)(y0 + 1) >= NY) wy1 = 0.f;
    if ((wx0 == 0.f && wx1 == 0.f) || (wy0 == 0.f && wy1 == 0.f)) return;
    int cx0 = min(max(x0, 0), NX - 1);
    int cx1 = min(max(x0 + 1, 0), NX - 1);
    int cy0 = min(max(y0, 0), NY - 1);
    int cy1 = min(max(y0 + 1, 0), NY - 1);
    uint4 q00 = *(const uint4*)(base + ((size_t)((cy0 << 8) + cx0) << 6));
    uint4 q01 = *(const uint4*)(base + ((size_t)((cy0 << 8) + cx1) << 6));
    uint4 q10 = *(const uint4*)(base + ((size_t)((cy1 << 8) + cx0) << 6));
    uint4 q11 = *(const uint4*)(base + ((size_t)((cy1 << 8) + cx1) << 6));
    acc8h(acc, q00, wy0 * wx0);
    acc8h(acc, q01, wy0 * wx1);
    acc8h(acc, q10, wy1 * wx0);
    acc8h(acc, q11, wy1 * wx1);
}

// ---------------------------------------------------------------------------
// K2: forward projection (round-7 config: per-ray slicing, v_fma_mix, no pipeline).
// grid (4 u-groups, C ray-slices, A), block 256
__global__ __launch_bounds__(256) void k_forward(const unsigned short* __restrict__ vol_h,
                                                 const float* __restrict__ trig,
                                                 float* __restrict__ part) {
    const int tid = threadIdx.x;
    const int a   = blockIdx.z;
    const int u   = blockIdx.x * 64 + (tid >> 2);
    const int zq  = tid & 3;
    const int cid = blockIdx.y;
    const int C   = gridDim.y;

    const float c = trig[2 * a];
    const float s = trig[2 * a + 1];
    const float uu = (float)u - 127.5f;
    const float bx = fmaf(-uu, s, 127.5f);
    const float by = fmaf(uu, c, 127.5f);

    float lo1, hi1, lo2, hi2;
    rng(c, bx, -1.f, 256.f, lo1, hi1);
    rng(s, by, -1.f, 256.f, lo2, hi2);
    float fl = fmaxf(lo1, lo2), fh = fminf(hi1, hi2);
    int F0 = max(0,     clampi(ceilf(fl + 127.5f)));
    int F1 = min(T - 1, clampi(floorf(fh + 127.5f)));
    int len = F1 - F0 + 1; if (len < 0) len = 0;
    int b0 = F0 + (len * cid) / C;
    int b1 = F0 + (len * (cid + 1)) / C - 1;
    rng(c, bx, 1.f, 253.5f, lo1, hi1);
    rng(s, by, 1.f, 253.5f, lo2, hi2);
    float il = fmaxf(lo1, lo2), ih = fminf(hi1, hi2);
    int tI0 = max(clampi(ceilf(il + 127.5f)) + 1, b0);
    int tI1 = min(clampi(floorf(ih + 127.5f)) - 1, b1);
    if (tI0 > tI1) { tI0 = b1 + 1; tI1 = b1; }

    const char* base = (const char*)vol_h + zq * 16;
    float acc[8];
    #pragma unroll
    for (int k = 0; k < 8; ++k) acc[k] = 0.f;

    for (int t = b0; t < tI0; ++t) {
        float ttf = (float)t - 127.5f;
        sample_edge(base, fmaf(ttf, c, bx), fmaf(ttf, s, by), acc);
    }
    for (int t = tI0; t <= tI1; ++t) {
        float ttf = (float)t - 127.5f;
        float ix = fmaf(ttf, c, bx);
        float iy = fmaf(ttf, s, by);
        float xf = floorf(ix), yf = floorf(iy);
        float fx = ix - xf, fy = iy - yf;
        int row = ((int)yf << 8) + (int)xf;
        const char* p0 = base + ((size_t)row << 6);
        uint4 q00 = *(const uint4*)(p0);
        uint4 q01 = *(const uint4*)(p0 + 64);
        uint4 q10 = *(const uint4*)(p0 + 16384);
        uint4 q11 = *(const uint4*)(p0 + 16384 + 64);
        float wx0 = 1.f - fx, wy0 = 1.f - fy;
        acc8h(acc, q00, wy0 * wx0);
        acc8h(acc, q01, wy0 * fx);
        acc8h(acc, q10, fy * wx0);
        acc8h(acc, q11, fy * fx);
    }
    for (int t = tI1 + 1; t <= b1; ++t) {
        float ttf = (float)t - 127.5f;
        sample_edge(base, fmaf(ttf, c, bx), fmaf(ttf, s, by), acc);
    }

    float4* dst = (float4*)(part + (size_t)cid * RES_ELEMS +
                            ((a * DET0 + u) * NZ + zq * 8));
    dst[0] = make_float4(acc[0], acc[1], acc[2], acc[3]);
    dst[1] = make_float4(acc[4], acc[5], acc[6], acc[7]);
}

// ---------------------------------------------------------------------------
// K3: res_t(f16, seeded -p_perm) += sum_c part[c](f32); repack to f16.
// Thread handles 8 halves (one uint4). grid (RES_ELEMS/8/256 = 384), block 256
__global__ __launch_bounds__(256) void k_combine(const float* __restrict__ part,
                                                 unsigned short* __restrict__ res_t,
                                                 int C) {
    const int j8 = blockIdx.x * 256 + threadIdx.x;   // unit of 8 halves
    uint4 rv = *(const uint4*)(res_t + j8 * 8);
    float2 f0 = unp2h(rv.x), f1 = unp2h(rv.y), f2 = unp2h(rv.z), f3 = unp2h(rv.w);
    float o[8] = {f0.x, f0.y, f1.x, f1.y, f2.x, f2.y, f3.x, f3.y};
    for (int c = 0; c < C; ++c) {
        const float4* pp = (const float4*)(part + (size_t)c * RES_ELEMS) + j8 * 2;
        float4 w0 = pp[0], w1 = pp[1];
        o[0] += w0.x; o[1] += w0.y; o[2] += w0.z; o[3] += w0.w;
        o[4] += w1.x; o[5] += w1.y; o[6] += w1.z; o[7] += w1.w;
    }
    uint4 pk = make_uint4(pack2h(o[0], o[1]), pack2h(o[2], o[3]),
                          pack2h(o[4], o[5]), pack2h(o[6], o[7]));
    *(uint4*)(res_t + j8 * 8) = pk;
}

// ---------------------------------------------------------------------------
// K4: backprojection v5 — f16 res_t (rows 64 B: halves the 1.6 GB L2 traffic
// that bounds this kernel) + inline weights (no tables), 4.2 KB LDS ->
// 8 blocks/CU. Taps = uint2 (4 halves) accumulated via forced v_fma_mix_f32.
// thread = (xs = tid>>3 of 32, zq = tid&7; 4 z per lane). grid (NX/32, NY).
// Zero-weight clamped taps may read the trig padding harmlessly (-64B stays in ws).
__global__ __launch_bounds__(256, 8) void k_backward(const unsigned short* __restrict__ res_t,
                                                     const float* __restrict__ trig,
                                                     float* __restrict__ out) {
    __shared__ float ob[32 * 33];   // 4,224 B output staging
    const int tid = threadIdx.x;
    const int y  = blockIdx.y;
    const int xb = blockIdx.x * 32;
    const int xs = tid >> 3;
    const int zq = tid & 7;          // 4 z per lane
    const char* rbase = (const char*)res_t + zq * 8;
    const float xx = (float)(xb + xs) - 127.5f;
    const float yy = (float)y - 127.5f;

    float4 acc = make_float4(0.f, 0.f, 0.f, 0.f);
    #pragma unroll 4
    for (int a = 0; a < A; ++a) {
        float cc = trig[2 * a];      // uniform -> scalar loads
        float ss = trig[2 * a + 1];
        float ub = fmaf(-xx, ss, fmaf(yy, cc, 127.5f));
        float uf = floorf(ub);
        float fu = ub - uf;
        int i0 = (int)uf;
        float w0 = ((unsigned)i0 < DET0) ? (1.f - fu) : 0.f;
        float w1 = ((unsigned)(i0 + 1) < DET0) ? fu : 0.f;
        int c1 = min(max(i0 + 1, 0), DET0);       // 0..256; tap0 row = c1-1
        int off = ((a * DET0 + c1) * NZ - NZ) << 1;   // byte offset (f16 rows, 64 B)
        uint2 v0 = *(const uint2*)(rbase + off);
        uint2 v1 = *(const uint2*)(rbase + off + 64);
        accp_mix(acc.x, acc.y, v0.x, w0);
        accp_mix(acc.z, acc.w, v0.y, w0);
        accp_mix(acc.x, acc.y, v1.x, w1);
        accp_mix(acc.z, acc.w, v1.y, w1);
    }

    ob[(zq * 4 + 0) * 33 + xs] = acc.x;
    ob[(zq * 4 + 1) * 33 + xs] = acc.y;
    ob[(zq * 4 + 2) * 33 + xs] = acc.z;
    ob[(zq * 4 + 3) * 33 + xs] = acc.w;
    __syncthreads();

    const int z  = tid >> 3;
    const int x4 = (tid & 7) * 4;
    float4 o = make_float4(ob[z * 33 + x4],     ob[z * 33 + x4 + 1],
                           ob[z * 33 + x4 + 2], ob[z * 33 + x4 + 3]);
    float4* dst = (float4*)(out + (size_t)z * (NY * NX) + y * NX + xb + x4);
    *dst = make_float4(-LAMB * o.x, -LAMB * o.y, -LAMB * o.z, -LAMB * o.w);
}

// ---------------------------------------------------------------------------
extern "C" void kernel_launch(void* const* d_in, const int* in_sizes, int n_in,
                              void* d_out, int out_size, void* d_ws, size_t ws_size,
                              hipStream_t stream) {
    const float* x = (const float*)d_in[0];   // (1,1,32,256,256)
    const float* p = (const float*)d_in[1];   // (1,1,384,8,256)
    float* out = (float*)d_out;               // (1,1,32,256,256)
    float* ws  = (float*)d_ws;

    float*          trig  = ws + TRIG_OFF;
    unsigned short* res_t = (unsigned short*)(ws + REST_OFF);
    unsigned short* vol_h = (unsigned short*)(ws + VOLB_OFF);
    float*          part  = ws + PART_OFF;

    size_t avail = ws_size / 4;
    int C = 8;
    while (C > 1 && (size_t)PART_OFF + (size_t)C * RES_ELEMS > avail) C >>= 1;

    k_transpose<<<dim3(NX / 64, NY), 256, 0, stream>>>(x, vol_h, trig, p, res_t);
    k_forward  <<<dim3(4, C, A), 256, 0, stream>>>(vol_h, trig, part);
    k_combine  <<<dim3(RES_ELEMS / 8 / 256), 256, 0, stream>>>(part, res_t, C);
    k_backward <<<dim3(NX / 32, NY), 256, 0, stream>>>(res_t, trig, out);
}